// Round 3
// baseline (6587.898 us; speedup 1.0000x reference)
//
#include <hip/hip_runtime.h>
#include <hip/hip_bf16.h>

// Grouped Residual VQ: G=2, Q=8, K=1024, CD=256, DIM=1280 (DG=640), T=32768.
//
// Argmin strategy: f32 fast scan tracks (best, idx, second-best); tokens with
// gap < EPS are re-scanned over all 1024 codes in f64 (exact for f32 inputs)
// -> exact argmin, independent of accumulation order. Elementwise STE path
// (quant = fl(r + fl(c-r)), res = fl(r - quant), qout += quant) replicated.
//
// ws layout (floats):
//   h/qout [G][T][CD] | res [G][T][CD] | cnorm f32 [G][Q][K]
//   cn64  f64 [G][Q][K] | lpartD f64 [G][Q][256]

#define G 2
#define Q 8
#define KCODES 1024
#define CD 256
#define DIMV 1280
#define DG 640
#define T 32768

#define WS_H      ((size_t)0)
#define WS_RES    (WS_H + (size_t)G*T*CD)
#define WS_CNORM  (WS_RES + (size_t)G*T*CD)
#define WS_CN64   (WS_CNORM + (size_t)G*Q*KCODES)            // doubles (even f32 offset)
#define WS_LPARTD (WS_CN64 + (size_t)2*G*Q*KCODES)           // doubles

#define OUT_IDX   ((size_t)T*DIMV)
#define OUT_LOSS  (OUT_IDX + (size_t)G*T*Q)

#define EPS_REFINE 4e-3f

// numpy-pairwise-ish sum of squares of 128 floats (order only matters at ulp level)
__device__ __forceinline__ float np_half_sumsq(const float4* __restrict__ p) {
    float4 a = p[0], b = p[1];
    float r0=a.x*a.x, r1=a.y*a.y, r2=a.z*a.z, r3=a.w*a.w;
    float r4=b.x*b.x, r5=b.y*b.y, r6=b.z*b.z, r7=b.w*b.w;
#pragma unroll
    for (int i = 1; i < 16; i++) {
        a = p[2*i]; b = p[2*i+1];
        r0 += a.x*a.x; r1 += a.y*a.y; r2 += a.z*a.z; r3 += a.w*a.w;
        r4 += b.x*b.x; r5 += b.y*b.y; r6 += b.z*b.z; r7 += b.w*b.w;
    }
    return ((r0+r1)+(r2+r3)) + ((r4+r5)+(r6+r7));
}

// ---------------- K1: codebook norms (f32 + exact f64) ----------------
__global__ void k_norms(const float* __restrict__ cb, float* __restrict__ ws) {
    int r = blockIdx.x * 256 + threadIdx.x;          // 0 .. G*Q*K-1
    const float4* row = (const float4*)(cb + (size_t)r * CD);
    ws[WS_CNORM + r] = np_half_sumsq(row) + np_half_sumsq(row + 32);
    double s0=0, s1=0, s2=0, s3=0;
#pragma unroll 8
    for (int e = 0; e < 64; e++) {
        float4 v = row[e];
        s0 = fma((double)v.x, (double)v.x, s0);
        s1 = fma((double)v.y, (double)v.y, s1);
        s2 = fma((double)v.z, (double)v.z, s2);
        s3 = fma((double)v.w, (double)v.w, s3);
    }
    ((double*)(ws + WS_CN64))[r] = (s0+s1)+(s2+s3);
}

// ---------------- K2: input projection h = x_g @ Win_g^T + bin ----------------
__global__ __launch_bounds__(256) void k_proj_in(const float* __restrict__ x,
                                                 const float* __restrict__ Win,
                                                 const float* __restrict__ bin,
                                                 float* __restrict__ ws) {
    __shared__ float As[32][65];
    __shared__ float Bs[32][65];
    const int g  = blockIdx.z;
    const int t0 = blockIdx.x * 64;
    const int c0 = blockIdx.y * 64;
    const int tid = threadIdx.x;
    const int tx = tid & 15, ty = tid >> 4;
    float acc[4][4] = {};
    const float* Ab = x + (size_t)t0 * DIMV + (size_t)g * DG;
    const float* Bb = Win + (size_t)g * CD * DG + (size_t)c0 * DG;

    for (int k0 = 0; k0 < DG; k0 += 32) {
        __syncthreads();
#pragma unroll
        for (int j = 0; j < 8; j++) {
            int lin = j * 256 + tid;
            int k = lin & 31, r = lin >> 5;
            As[k][r] = Ab[(size_t)r * DIMV + k0 + k];
            Bs[k][r] = Bb[(size_t)r * DG + k0 + k];
        }
        __syncthreads();
#pragma unroll
        for (int k = 0; k < 32; k++) {
            float a[4], b[4];
#pragma unroll
            for (int i = 0; i < 4; i++) a[i] = As[k][ty + 16 * i];
#pragma unroll
            for (int j = 0; j < 4; j++) b[j] = Bs[k][tx + 16 * j];
#pragma unroll
            for (int i = 0; i < 4; i++)
#pragma unroll
                for (int j = 0; j < 4; j++) acc[i][j] = fmaf(a[i], b[j], acc[i][j]);
        }
    }
#pragma unroll
    for (int i = 0; i < 4; i++) {
        int t = t0 + ty + 16 * i;
        float* hrow = ws + WS_H + ((size_t)g * T + t) * CD;
#pragma unroll
        for (int j = 0; j < 4; j++) {
            int c = c0 + tx + 16 * j;
            hrow[c] = acc[i][j] + bin[g * CD + c];
        }
    }
}

// ---------------- K3: fused ResidualVQ ----------------
#define TM 128
#define NCC 128

__global__ __launch_bounds__(256, 2) void k_rvq(const float* __restrict__ cb,
                                                float* __restrict__ ws,
                                                float* __restrict__ out) {
    __shared__ float4 Rs[TM * 16];     // [row][16 f4], idx = row*16 + (d4 ^ (row&15))
    __shared__ float4 Cs[NCC * 16];
    __shared__ float  rnS[TM];
    __shared__ double lredD[4];
    const int g  = blockIdx.y;
    const int t0 = blockIdx.x * TM;
    const int tid = threadIdx.x;
    const int tx = tid & 15, ty = tid >> 4;
    const size_t gT = (size_t)g * T;
    float* hbuf = ws + WS_H;                       // becomes qout accumulator
    float* rbuf = ws + WS_RES;
    const float* cng = ws + WS_CNORM + (size_t)g * Q * KCODES;
    double* lpD = (double*)(ws + WS_LPARTD);

    for (int q = 0; q < Q; q++) {
        const float* rsrc = (q == 0) ? hbuf : rbuf;
        const float* cnq = cng + (size_t)q * KCODES;
        const double* cn64q = (const double*)(ws + WS_CN64) + ((size_t)g * Q + q) * KCODES;
        const float* cqb = cb + ((size_t)g * Q + q) * KCODES * CD;

        // ---- rn = sum(r*r), 2 threads per token ----
        {
            int tk = tid >> 1, half = tid & 1;
            const float4* p = (const float4*)(rsrc + (gT + t0 + tk) * CD) + half * 32;
            float hs = np_half_sumsq(p);
            float other = __shfl_xor(hs, 1, 64);
            if (half == 0) rnS[tk] = hs + other;
        }
        __syncthreads();
        float rn[8];
#pragma unroll
        for (int i = 0; i < 8; i++) rn[i] = rnS[ty + 16 * i];

        // per-thread running (best, idx, second-best) over all candidates
        float bestv[8], bestv2[8];
        int   besti[8];
#pragma unroll
        for (int i = 0; i < 8; i++) { bestv[i] = 3.4e38f; bestv2[i] = 3.4e38f; besti[i] = 0x7fffffff; }

        for (int cc = 0; cc < KCODES / NCC; cc++) {
            float S[8][8] = {};
            for (int dc = 0; dc < CD / 64; dc++) {
                __syncthreads();
#pragma unroll
                for (int s8 = 0; s8 < 8; s8++) {       // stage Rs: 128 rows x 16 f4
                    int lin = s8 * 256 + tid;
                    int row = lin >> 4, d4 = lin & 15;
                    const float4* src = (const float4*)(rsrc + (gT + t0 + row) * CD) + dc * 16 + d4;
                    Rs[row * 16 + (d4 ^ (row & 15))] = *src;
                }
#pragma unroll
                for (int s8 = 0; s8 < 8; s8++) {       // stage Cs
                    int lin = s8 * 256 + tid;
                    int row = lin >> 4, d4 = lin & 15;
                    const float4* src = (const float4*)(cqb + (size_t)(cc * NCC + row) * CD) + dc * 16 + d4;
                    Cs[row * 16 + (d4 ^ (row & 15))] = *src;
                }
                __syncthreads();
#pragma unroll 1
                for (int d4 = 0; d4 < 16; d4++) {
                    float4 rf[8], cf[8];
#pragma unroll
                    for (int i = 0; i < 8; i++) {
                        int row = ty + 16 * i;
                        rf[i] = Rs[row * 16 + (d4 ^ (row & 15))];
                    }
#pragma unroll
                    for (int j = 0; j < 8; j++) {
                        int row = tx + 16 * j;
                        cf[j] = Cs[row * 16 + (d4 ^ (row & 15))];
                    }
#pragma unroll
                    for (int i = 0; i < 8; i++)
#pragma unroll
                        for (int j = 0; j < 8; j++) {
                            float s = S[i][j];
                            s = fmaf(rf[i].x, cf[j].x, s);
                            s = fmaf(rf[i].y, cf[j].y, s);
                            s = fmaf(rf[i].z, cf[j].z, s);
                            s = fmaf(rf[i].w, cf[j].w, s);
                            S[i][j] = s;
                        }
                }
            }
            // ---- two-min candidate updates (thread-local; c ascending) ----
#pragma unroll
            for (int i = 0; i < 8; i++) {
#pragma unroll
                for (int j = 0; j < 8; j++) {
                    int c = cc * NCC + tx + 16 * j;
                    float vv = (rn[i] - 2.f * S[i][j]) + cnq[cc * NCC + tx + 16 * j];
                    if (vv < bestv[i])            { bestv2[i] = bestv[i]; bestv[i] = vv; besti[i] = c; }
                    else if (vv == bestv[i])      { bestv2[i] = bestv[i]; if (c < besti[i]) besti[i] = c; }
                    else if (vv < bestv2[i])      { bestv2[i] = vv; }
                }
            }
        }

        // ---- cross-lane two-min butterfly over the 16 tx lanes ----
#pragma unroll
        for (int i = 0; i < 8; i++) {
            float v1 = bestv[i], v2 = bestv2[i];
            int   i1 = besti[i];
#pragma unroll
            for (int m = 1; m < 16; m <<= 1) {
                float w1 = __shfl_xor(v1, m, 64);
                float w2 = __shfl_xor(v2, m, 64);
                int   j1 = __shfl_xor(i1, m, 64);
                if (w1 < v1)        { v2 = fminf(v1, w2); v1 = w1; i1 = j1; }
                else if (w1 == v1)  { v2 = v1; if (j1 < i1) i1 = j1; }
                else                { v2 = fminf(v2, w1); }
            }
            bestv[i] = v1; bestv2[i] = v2; besti[i] = i1;
        }

        // ---- exact f64 refinement for near-tie tokens (rare) ----
#pragma unroll 1
        for (int i = 0; i < 8; i++) {
            if (!(bestv2[i] - bestv[i] < EPS_REFINE)) continue;   // uniform across tx
            const float* rrow = rsrc + (gT + t0 + ty + 16 * i) * CD;
            const float4* rp4 = (const float4*)rrow;
            double s0=0, s1=0, s2=0, s3=0;
#pragma unroll 4
            for (int e = 0; e < 64; e++) {
                float4 v = rp4[e];
                s0 = fma((double)v.x,(double)v.x,s0); s1 = fma((double)v.y,(double)v.y,s1);
                s2 = fma((double)v.z,(double)v.z,s2); s3 = fma((double)v.w,(double)v.w,s3);
            }
            double rn64 = (s0+s1)+(s2+s3);
            double bv = 1e300; int bi = 0x7fffffff;
            for (int c = tx; c < KCODES; c += 16) {
                const float4* cp4 = (const float4*)(cqb + (size_t)c * CD);
                double a0=0, a1=0, a2=0, a3=0;
#pragma unroll 4
                for (int e = 0; e < 64; e++) {
                    float4 cv = cp4[e], rv = rp4[e];
                    a0 = fma((double)rv.x,(double)cv.x,a0); a1 = fma((double)rv.y,(double)cv.y,a1);
                    a2 = fma((double)rv.z,(double)cv.z,a2); a3 = fma((double)rv.w,(double)cv.w,a3);
                }
                double dd = fma(-2.0, (a0+a1)+(a2+a3), rn64) + cn64q[c];
                if (dd < bv) { bv = dd; bi = c; }           // strided -> first-index kept per lane
            }
#pragma unroll
            for (int m = 1; m < 16; m <<= 1) {
                double ov = __shfl_xor(bv, m, 64);
                int    oi = __shfl_xor(bi, m, 64);
                if (ov < bv || (ov == bv && oi < bi)) { bv = ov; bi = oi; }
            }
            besti[i] = bi;
        }

        // ---- idx out ----
        if (tx == 0) {
#pragma unroll
            for (int i = 0; i < 8; i++)
                out[OUT_IDX + (gT + t0 + ty + 16 * i) * Q + q] = (float)besti[i];
        }

        // ---- STE epilogue: quant/res/qout rounding-replicated; loss from res ----
        double lacc = 0.0;
#pragma unroll
        for (int i = 0; i < 8; i++) {
            int t = ty + 16 * i;
            size_t off = (gT + t0 + t) * CD;
            const float4* cp = (const float4*)(cb + ((size_t)g * Q + q) * KCODES * CD
                                               + (size_t)besti[i] * CD) + tx * 4;
            const float4* rp = (const float4*)(rsrc + off) + tx * 4;
            float4* wp = (float4*)(rbuf + off) + tx * 4;
            float4* qp = (float4*)(hbuf + off) + tx * 4;   // aliases rp when q==0 (read-before-write per thread)
#pragma unroll
            for (int e = 0; e < 4; e++) {
                float4 c4 = cp[e], r4 = rp[e];
                float4 q4 = (q == 0) ? make_float4(0.f,0.f,0.f,0.f) : qp[e];
                float4 res4, qo4;
                float tt, qq, rr;
                tt = __fsub_rn(c4.x, r4.x); qq = __fadd_rn(r4.x, tt); rr = __fsub_rn(r4.x, qq);
                lacc += (double)rr * rr; res4.x = rr; qo4.x = (q==0) ? qq : __fadd_rn(q4.x, qq);
                tt = __fsub_rn(c4.y, r4.y); qq = __fadd_rn(r4.y, tt); rr = __fsub_rn(r4.y, qq);
                lacc += (double)rr * rr; res4.y = rr; qo4.y = (q==0) ? qq : __fadd_rn(q4.y, qq);
                tt = __fsub_rn(c4.z, r4.z); qq = __fadd_rn(r4.z, tt); rr = __fsub_rn(r4.z, qq);
                lacc += (double)rr * rr; res4.z = rr; qo4.z = (q==0) ? qq : __fadd_rn(q4.z, qq);
                tt = __fsub_rn(c4.w, r4.w); qq = __fadd_rn(r4.w, tt); rr = __fsub_rn(r4.w, qq);
                lacc += (double)rr * rr; res4.w = rr; qo4.w = (q==0) ? qq : __fadd_rn(q4.w, qq);
                wp[e] = res4;
                qp[e] = qo4;
            }
        }
        // deterministic loss partial (f64)
#pragma unroll
        for (int m = 1; m < 64; m <<= 1) lacc += __shfl_xor(lacc, m, 64);
        __syncthreads();
        if ((tid & 63) == 0) lredD[tid >> 6] = lacc;
        __syncthreads();
        if (tid == 0)
            lpD[((size_t)g * Q + q) * 256 + blockIdx.x] =
                ((lredD[0] + lredD[1]) + (lredD[2] + lredD[3]));
        __threadfence_block();
        __syncthreads();
    }
}

// ---------------- K4: output projection out = qout @ Wout_g^T + bout ----------------
__global__ __launch_bounds__(256) void k_proj_out(const float* __restrict__ ws,
                                                  const float* __restrict__ Wout,
                                                  const float* __restrict__ bout,
                                                  float* __restrict__ out) {
    __shared__ float As[32][65];
    __shared__ float Bs[32][65];
    const int g  = blockIdx.z;
    const int t0 = blockIdx.x * 64;
    const int d0 = blockIdx.y * 64;
    const int tid = threadIdx.x;
    const int tx = tid & 15, ty = tid >> 4;
    float acc[4][4] = {};
    const float* Ab = ws + WS_H + ((size_t)g * T + t0) * CD;
    const float* Bb = Wout + (size_t)g * DG * CD + (size_t)d0 * CD;

    for (int k0 = 0; k0 < CD; k0 += 32) {
        __syncthreads();
#pragma unroll
        for (int j = 0; j < 8; j++) {
            int lin = j * 256 + tid;
            int k = lin & 31, r = lin >> 5;
            As[k][r] = Ab[(size_t)r * CD + k0 + k];
            Bs[k][r] = Bb[(size_t)r * CD + k0 + k];
        }
        __syncthreads();
#pragma unroll
        for (int k = 0; k < 32; k++) {
            float a[4], b[4];
#pragma unroll
            for (int i = 0; i < 4; i++) a[i] = As[k][ty + 16 * i];
#pragma unroll
            for (int j = 0; j < 4; j++) b[j] = Bs[k][tx + 16 * j];
#pragma unroll
            for (int i = 0; i < 4; i++)
#pragma unroll
                for (int j = 0; j < 4; j++) acc[i][j] = fmaf(a[i], b[j], acc[i][j]);
        }
    }
#pragma unroll
    for (int i = 0; i < 4; i++) {
        int t = t0 + ty + 16 * i;
#pragma unroll
        for (int j = 0; j < 4; j++) {
            int d = d0 + tx + 16 * j;
            out[(size_t)t * DIMV + (size_t)g * DG + d] = acc[i][j] + bout[g * DG + d];
        }
    }
}

// ---------------- K5: deterministic loss reduction (f64 -> f32) ----------------
__global__ void k_loss(const float* __restrict__ ws, float* __restrict__ out) {
    int gq = blockIdx.x;                       // g*Q+q, 0..15
    const double* lpD = (const double*)(ws + WS_LPARTD);
    double v = lpD[(size_t)gq * 256 + threadIdx.x];
#pragma unroll
    for (int m = 1; m < 64; m <<= 1) v += __shfl_xor(v, m, 64);
    __shared__ double red[4];
    if ((threadIdx.x & 63) == 0) red[threadIdx.x >> 6] = v;
    __syncthreads();
    if (threadIdx.x == 0)
        out[OUT_LOSS + gq] =
            (float)(((red[0] + red[1]) + (red[2] + red[3])) * (1.0 / 8388608.0));
}

extern "C" void kernel_launch(void* const* d_in, const int* in_sizes, int n_in,
                              void* d_out, int out_size, void* d_ws, size_t ws_size,
                              hipStream_t stream) {
    const float* x    = (const float*)d_in[0];
    const float* Win  = (const float*)d_in[1];
    const float* bin  = (const float*)d_in[2];
    const float* Wout = (const float*)d_in[3];
    const float* bout = (const float*)d_in[4];
    const float* cb   = (const float*)d_in[5];
    float* out = (float*)d_out;
    float* ws  = (float*)d_ws;

    hipLaunchKernelGGL(k_norms,    dim3(64),          dim3(256), 0, stream, cb, ws);
    hipLaunchKernelGGL(k_proj_in,  dim3(T/64, 4, G),  dim3(256), 0, stream, x, Win, bin, ws);
    hipLaunchKernelGGL(k_rvq,      dim3(T/TM, G),     dim3(256), 0, stream, cb, ws, out);
    hipLaunchKernelGGL(k_proj_out, dim3(T/64, 10, G), dim3(256), 0, stream, ws, Wout, bout, out);
    hipLaunchKernelGGL(k_loss,     dim3(16),          dim3(256), 0, stream, ws, out);
}

// Round 4
// 4142.402 us; speedup vs baseline: 1.5904x; 1.5904x over previous
//
#include <hip/hip_runtime.h>
#include <hip/hip_bf16.h>

// Grouped Residual VQ: G=2, Q=8, K=1024, CD=256, DIM=1280 (DG=640), T=32768.
//
// Fast path: distance GEMM via bf16 3-term split MFMA (error ~1e-4 << EPS);
// tokens with (second-best - best) < EPS get an exact f64 rescan of all 1024
// codes -> exact argmin regardless of accumulation order. STE elementwise
// rounding (quant = fl(r + fl(c-r)), res = fl(r-quant), qout += quant)
// replicated as in the passing round-3 kernel.
//
// ws (floats): h/qout [G][T][CD] | res [G][T][CD] | cnorm f32 | cn64 f64 | lpart f64
// d_out quantized region doubles as scratch for bf16 hi/lo splits of residual
// and codebook (21M f32-equiv < 41.9M region; k_proj_out overwrites at end).

#define G 2
#define Q 8
#define KCODES 1024
#define CD 256
#define DIMV 1280
#define DG 640
#define T 32768
#define TM 128

#define WS_H      ((size_t)0)
#define WS_RES    (WS_H + (size_t)G*T*CD)
#define WS_CNORM  (WS_RES + (size_t)G*T*CD)
#define WS_CN64   (WS_CNORM + (size_t)G*Q*KCODES)
#define WS_LPARTD (WS_CN64 + (size_t)2*G*Q*KCODES)

#define OUT_IDX   ((size_t)T*DIMV)
#define OUT_LOSS  (OUT_IDX + (size_t)G*T*Q)

#define EPS_REFINE 2e-3f

typedef __attribute__((ext_vector_type(8))) short s16x8;
typedef __attribute__((ext_vector_type(4))) float f32x4;

static __device__ __forceinline__ unsigned short f2bf(float v) {
    __hip_bfloat16 b = __float2bfloat16(v);
    return *(unsigned short*)&b;
}
static __device__ __forceinline__ float bf2f(unsigned short u) {
    __hip_bfloat16 b = *(__hip_bfloat16*)&u;
    return __bfloat162float(b);
}

__device__ __forceinline__ float np_half_sumsq(const float4* __restrict__ p) {
    float4 a = p[0], b = p[1];
    float r0=a.x*a.x, r1=a.y*a.y, r2=a.z*a.z, r3=a.w*a.w;
    float r4=b.x*b.x, r5=b.y*b.y, r6=b.z*b.z, r7=b.w*b.w;
#pragma unroll
    for (int i = 1; i < 16; i++) {
        a = p[2*i]; b = p[2*i+1];
        r0 += a.x*a.x; r1 += a.y*a.y; r2 += a.z*a.z; r3 += a.w*a.w;
        r4 += b.x*b.x; r5 += b.y*b.y; r6 += b.z*b.z; r7 += b.w*b.w;
    }
    return ((r0+r1)+(r2+r3)) + ((r4+r5)+(r6+r7));
}

// ---------------- K1: codebook norms (f32 + exact f64) ----------------
__global__ void k_norms(const float* __restrict__ cb, float* __restrict__ ws) {
    int r = blockIdx.x * 256 + threadIdx.x;
    const float4* row = (const float4*)(cb + (size_t)r * CD);
    ws[WS_CNORM + r] = np_half_sumsq(row) + np_half_sumsq(row + 32);
    double s0=0, s1=0, s2=0, s3=0;
#pragma unroll 8
    for (int e = 0; e < 64; e++) {
        float4 v = row[e];
        s0 = fma((double)v.x,(double)v.x,s0); s1 = fma((double)v.y,(double)v.y,s1);
        s2 = fma((double)v.z,(double)v.z,s2); s3 = fma((double)v.w,(double)v.w,s3);
    }
    ((double*)(ws + WS_CN64))[r] = (s0+s1)+(s2+s3);
}

// ---------------- K1b: codebook bf16 hi/lo split ----------------
__global__ void k_split(const float* __restrict__ cb, short* __restrict__ cbh,
                        short* __restrict__ cbl) {
    size_t i = ((size_t)blockIdx.x * 256 + threadIdx.x) * 4;   // over G*Q*K*CD
    float4 v = *(const float4*)(cb + i);
    unsigned short h0=f2bf(v.x), h1=f2bf(v.y), h2=f2bf(v.z), h3=f2bf(v.w);
    short4 hh = make_short4((short)h0,(short)h1,(short)h2,(short)h3);
    short4 ll = make_short4((short)f2bf(v.x - bf2f(h0)), (short)f2bf(v.y - bf2f(h1)),
                            (short)f2bf(v.z - bf2f(h2)), (short)f2bf(v.w - bf2f(h3)));
    *(short4*)(cbh + i) = hh;
    *(short4*)(cbl + i) = ll;
}

// ---------------- K2: input projection h = x_g @ Win_g^T + bin (+ bf16 split) ----------------
__global__ __launch_bounds__(256) void k_proj_in(const float* __restrict__ x,
                                                 const float* __restrict__ Win,
                                                 const float* __restrict__ bin,
                                                 float* __restrict__ ws,
                                                 short* __restrict__ resh,
                                                 short* __restrict__ resl) {
    __shared__ float As[32][65];
    __shared__ float Bs[32][65];
    const int g  = blockIdx.z;
    const int t0 = blockIdx.x * 64;
    const int c0 = blockIdx.y * 64;
    const int tid = threadIdx.x;
    const int tx = tid & 15, ty = tid >> 4;
    float acc[4][4] = {};
    const float* Ab = x + (size_t)t0 * DIMV + (size_t)g * DG;
    const float* Bb = Win + (size_t)g * CD * DG + (size_t)c0 * DG;

    for (int k0 = 0; k0 < DG; k0 += 32) {
        __syncthreads();
#pragma unroll
        for (int j = 0; j < 8; j++) {
            int lin = j * 256 + tid;
            int k = lin & 31, r = lin >> 5;
            As[k][r] = Ab[(size_t)r * DIMV + k0 + k];
            Bs[k][r] = Bb[(size_t)r * DG + k0 + k];
        }
        __syncthreads();
#pragma unroll
        for (int k = 0; k < 32; k++) {
            float a[4], b[4];
#pragma unroll
            for (int i = 0; i < 4; i++) a[i] = As[k][ty + 16 * i];
#pragma unroll
            for (int j = 0; j < 4; j++) b[j] = Bs[k][tx + 16 * j];
#pragma unroll
            for (int i = 0; i < 4; i++)
#pragma unroll
                for (int j = 0; j < 4; j++) acc[i][j] = fmaf(a[i], b[j], acc[i][j]);
        }
    }
#pragma unroll
    for (int i = 0; i < 4; i++) {
        int t = t0 + ty + 16 * i;
        size_t roff = ((size_t)g * T + t) * CD;
        float* hrow = ws + WS_H + roff;
#pragma unroll
        for (int j = 0; j < 4; j++) {
            int c = c0 + tx + 16 * j;
            float v = acc[i][j] + bin[g * CD + c];
            hrow[c] = v;
            unsigned short hb = f2bf(v);
            resh[roff + c] = (short)hb;
            resl[roff + c] = (short)f2bf(v - bf2f(hb));
        }
    }
}

// ---------------- K3: fused ResidualVQ (MFMA bf16-split fast path) ----------------
__global__ __launch_bounds__(256, 2) void k_rvq(const float* __restrict__ cb,
                                                float* __restrict__ ws,
                                                float* __restrict__ out,
                                                short* __restrict__ resh,
                                                short* __restrict__ resl,
                                                const short* __restrict__ cbh,
                                                const short* __restrict__ cbl) {
    __shared__ s16x8 AsV[2048];        // [plane 2][row 128][8 units], unit idx swizzled
    __shared__ s16x8 BsV[2048];
    __shared__ float cnS[KCODES];
    __shared__ float rnS[TM];
    __shared__ float mmv1[TM], mmv2[TM];
    __shared__ int   mmi[TM];
    __shared__ double lredD[4];

    const int g  = blockIdx.y;
    const int t0 = blockIdx.x * TM;
    const int tid = threadIdx.x;
    const int lane = tid & 63, l15 = lane & 15, l4 = lane >> 4;
    const int w = tid >> 6, wy = w >> 1, wx = w & 1;
    const int tx = tid & 15, ty = tid >> 4;
    const size_t gT = (size_t)g * T;
    float* hbuf = ws + WS_H;                       // becomes qout accumulator
    float* rbuf = ws + WS_RES;
    const float* cng = ws + WS_CNORM + (size_t)g * Q * KCODES;
    double* lpD = (double*)(ws + WS_LPARTD);

    for (int q = 0; q < Q; q++) {
        const float* rsrc = (q == 0) ? hbuf : rbuf;
        const float* cnq = cng + (size_t)q * KCODES;
        const double* cn64q = (const double*)(ws + WS_CN64) + ((size_t)g * Q + q) * KCODES;
        const float* cqb = cb + ((size_t)g * Q + q) * KCODES * CD;
        const short* cbhq = cbh + ((size_t)g * Q + q) * KCODES * CD;
        const short* cblq = cbl + ((size_t)g * Q + q) * KCODES * CD;

        if (q == 0) {            // rn for first step (later steps: fused in epilogue)
            int tk = tid >> 1, half = tid & 1;
            const float4* p = (const float4*)(rsrc + (gT + t0 + tk) * CD) + half * 32;
            float hs = np_half_sumsq(p);
            float other = __shfl_xor(hs, 1, 64);
            if (half == 0) rnS[tk] = hs + other;
        }
#pragma unroll
        for (int p = 0; p < 4; p++) cnS[p * 256 + tid] = cnq[p * 256 + tid];
        __syncthreads();

        float rnr[16];
#pragma unroll
        for (int e = 0; e < 16; e++) rnr[e] = rnS[wy * 64 + (e >> 2) * 16 + l4 * 4 + (e & 3)];

        float tv1[16], tv2[16]; int tix[16];
#pragma unroll
        for (int e = 0; e < 16; e++) { tv1[e] = 3.4e38f; tv2[e] = 3.4e38f; tix[e] = 0x7fffffff; }

        for (int cc = 0; cc < KCODES / 128; cc++) {
            f32x4 acc[4][4];
#pragma unroll
            for (int i = 0; i < 4; i++)
#pragma unroll
                for (int j = 0; j < 4; j++) acc[i][j] = (f32x4){0.f, 0.f, 0.f, 0.f};

            for (int dc = 0; dc < 4; dc++) {
                __syncthreads();
                {   // stage A (residual rows, bf16 hi/lo) and B (code rows)
                    int rr0 = tid >> 3, c8 = tid & 7;
#pragma unroll
                    for (int p = 0; p < 4; p++) {
                        int rr = rr0 + p * 32;
                        size_t gi = (gT + t0 + rr) * CD + dc * 64 + c8 * 8;
                        int di = rr * 8 + (c8 ^ (rr & 7));
                        AsV[di]        = *(const s16x8*)(resh + gi);
                        AsV[1024 + di] = *(const s16x8*)(resl + gi);
                    }
#pragma unroll
                    for (int p = 0; p < 4; p++) {
                        int rr = rr0 + p * 32;
                        size_t gi = ((size_t)cc * 128 + rr) * CD + dc * 64 + c8 * 8;
                        int di = rr * 8 + (c8 ^ (rr & 7));
                        BsV[di]        = *(const s16x8*)(cbhq + gi);
                        BsV[1024 + di] = *(const s16x8*)(cblq + gi);
                    }
                }
                __syncthreads();
#pragma unroll
                for (int ks = 0; ks < 2; ks++) {
                    s16x8 ah[4], al[4];
#pragma unroll
                    for (int ti = 0; ti < 4; ti++) {
                        int r = wy * 64 + ti * 16 + l15;
                        int u = (ks * 4 + l4) ^ (r & 7);
                        ah[ti] = AsV[r * 8 + u];
                        al[ti] = AsV[1024 + r * 8 + u];
                    }
#pragma unroll
                    for (int tj = 0; tj < 4; tj++) {
                        int r = wx * 64 + tj * 16 + l15;
                        int u = (ks * 4 + l4) ^ (r & 7);
                        s16x8 bh = BsV[r * 8 + u];
                        s16x8 bl = BsV[1024 + r * 8 + u];
#pragma unroll
                        for (int ti = 0; ti < 4; ti++) {
                            acc[ti][tj] = __builtin_amdgcn_mfma_f32_16x16x32_bf16(ah[ti], bh, acc[ti][tj], 0, 0, 0);
                            acc[ti][tj] = __builtin_amdgcn_mfma_f32_16x16x32_bf16(ah[ti], bl, acc[ti][tj], 0, 0, 0);
                            acc[ti][tj] = __builtin_amdgcn_mfma_f32_16x16x32_bf16(al[ti], bh, acc[ti][tj], 0, 0, 0);
                        }
                    }
                }
            }
            // ---- scoring: vv = rn - 2S + cn; per-lane two-min (codes ascending) ----
#pragma unroll
            for (int tj = 0; tj < 4; tj++) {
                int c = cc * 128 + wx * 64 + tj * 16 + l15;
                float cnv = cnS[c];
#pragma unroll
                for (int e = 0; e < 16; e++) {
                    float vv = fmaf(-2.f, acc[e >> 2][tj][e & 3], rnr[e]) + cnv;
                    if (vv < tv1[e]) { tv2[e] = tv1[e]; tv1[e] = vv; tix[e] = c; }
                    else tv2[e] = fminf(tv2[e], vv);
                }
            }
        }

        // ---- cross-lane two-min butterfly (16 lanes sharing a token group) ----
#pragma unroll
        for (int e = 0; e < 16; e++) {
            float v1 = tv1[e], v2 = tv2[e]; int i1 = tix[e];
#pragma unroll
            for (int m = 1; m < 16; m <<= 1) {
                float w1 = __shfl_xor(v1, m, 64);
                float w2 = __shfl_xor(v2, m, 64);
                int   j1 = __shfl_xor(i1, m, 64);
                if (w1 < v1)       { v2 = fminf(v1, w2); v1 = w1; i1 = j1; }
                else if (w1 == v1) { v2 = v1; if (j1 < i1) i1 = j1; }
                else               { v2 = fminf(v2, w1); }
            }
            tv1[e] = v1; tv2[e] = v2; tix[e] = i1;
        }
        // ---- cross-wave (wx halves) merge via LDS ----
        if (wx == 0 && l15 == 0) {
#pragma unroll
            for (int e = 0; e < 16; e++) {
                int tok = wy * 64 + (e >> 2) * 16 + l4 * 4 + (e & 3);
                mmv1[tok] = tv1[e]; mmv2[tok] = tv2[e]; mmi[tok] = tix[e];
            }
        }
        __syncthreads();
        if (wx == 1 && l15 == 0) {
#pragma unroll
            for (int e = 0; e < 16; e++) {
                int tok = wy * 64 + (e >> 2) * 16 + l4 * 4 + (e & 3);
                float a1 = mmv1[tok], a2 = mmv2[tok]; int ai = mmi[tok];
                float b1 = tv1[e], b2 = tv2[e]; int bi = tix[e];
                if (b1 < a1)       { a2 = fminf(a1, b2); a1 = b1; ai = bi; }
                else if (b1 == a1) { a2 = a1; if (bi < ai) ai = bi; }
                else               { a2 = fminf(a2, b1); }
                mmv1[tok] = a1; mmv2[tok] = a2; mmi[tok] = ai;
            }
        }
        __syncthreads();

        // ---- exact f64 refinement for near-tie tokens ----
        int besti[8];
#pragma unroll 1
        for (int i = 0; i < 8; i++) {
            int tok = ty + 16 * i;
            besti[i] = mmi[tok];
            if (!(mmv2[tok] - mmv1[tok] < EPS_REFINE)) continue;
            const float4* rp4 = (const float4*)(rsrc + (gT + t0 + tok) * CD);
            double s0=0, s1=0, s2=0, s3=0;
#pragma unroll 4
            for (int e = 0; e < 64; e++) {
                float4 v = rp4[e];
                s0 = fma((double)v.x,(double)v.x,s0); s1 = fma((double)v.y,(double)v.y,s1);
                s2 = fma((double)v.z,(double)v.z,s2); s3 = fma((double)v.w,(double)v.w,s3);
            }
            double rn64 = (s0+s1)+(s2+s3);
            double bv = 1e300; int bi = 0x7fffffff;
            for (int c = tx; c < KCODES; c += 16) {
                const float4* cp4 = (const float4*)(cqb + (size_t)c * CD);
                double a0=0, a1=0, a2=0, a3=0;
#pragma unroll 4
                for (int e = 0; e < 64; e++) {
                    float4 cv = cp4[e], rv = rp4[e];
                    a0 = fma((double)rv.x,(double)cv.x,a0); a1 = fma((double)rv.y,(double)cv.y,a1);
                    a2 = fma((double)rv.z,(double)cv.z,a2); a3 = fma((double)rv.w,(double)cv.w,a3);
                }
                double dd = fma(-2.0, (a0+a1)+(a2+a3), rn64) + cn64q[c];
                if (dd < bv) { bv = dd; bi = c; }
            }
#pragma unroll
            for (int m = 1; m < 16; m <<= 1) {
                double ov = __shfl_xor(bv, m, 64);
                int    oi = __shfl_xor(bi, m, 64);
                if (ov < bv || (ov == bv && oi < bi)) { bv = ov; bi = oi; }
            }
            besti[i] = bi;
        }

        // ---- idx out ----
        if (tx == 0) {
#pragma unroll
            for (int i = 0; i < 8; i++)
                out[OUT_IDX + (gT + t0 + ty + 16 * i) * Q + q] = (float)besti[i];
        }

        // ---- STE epilogue: res/qout rounding-replicated; rn + bf16 split fused ----
        double lacc = 0.0;
#pragma unroll
        for (int i = 0; i < 8; i++) {
            int t = ty + 16 * i;
            size_t off = (gT + t0 + t) * CD;
            const float4* cp = (const float4*)(cqb + (size_t)besti[i] * CD) + tx * 4;
            const float4* rp = (const float4*)(rsrc + off) + tx * 4;
            float4* wp = (float4*)(rbuf + off) + tx * 4;
            float4* qp = (float4*)(hbuf + off) + tx * 4;   // aliases rp when q==0 (thread-local RAW ok)
            short* rhp = resh + off + tx * 16;
            short* rlp = resl + off + tx * 16;
            float rns = 0.f;
#pragma unroll
            for (int e = 0; e < 4; e++) {
                float4 c4 = cp[e], r4 = rp[e];
                float4 q4 = (q == 0) ? make_float4(0.f,0.f,0.f,0.f) : qp[e];
                float4 res4, qo4;
                float tt, qq, rr;
                tt = __fsub_rn(c4.x, r4.x); qq = __fadd_rn(r4.x, tt); rr = __fsub_rn(r4.x, qq);
                lacc += (double)rr * rr; rns = fmaf(rr, rr, rns); res4.x = rr; qo4.x = (q==0) ? qq : __fadd_rn(q4.x, qq);
                tt = __fsub_rn(c4.y, r4.y); qq = __fadd_rn(r4.y, tt); rr = __fsub_rn(r4.y, qq);
                lacc += (double)rr * rr; rns = fmaf(rr, rr, rns); res4.y = rr; qo4.y = (q==0) ? qq : __fadd_rn(q4.y, qq);
                tt = __fsub_rn(c4.z, r4.z); qq = __fadd_rn(r4.z, tt); rr = __fsub_rn(r4.z, qq);
                lacc += (double)rr * rr; rns = fmaf(rr, rr, rns); res4.z = rr; qo4.z = (q==0) ? qq : __fadd_rn(q4.z, qq);
                tt = __fsub_rn(c4.w, r4.w); qq = __fadd_rn(r4.w, tt); rr = __fsub_rn(r4.w, qq);
                lacc += (double)rr * rr; rns = fmaf(rr, rr, rns); res4.w = rr; qo4.w = (q==0) ? qq : __fadd_rn(q4.w, qq);
                wp[e] = res4;
                qp[e] = qo4;
                unsigned short h0=f2bf(res4.x), h1=f2bf(res4.y), h2=f2bf(res4.z), h3=f2bf(res4.w);
                *(short4*)(rhp + e*4) = make_short4((short)h0,(short)h1,(short)h2,(short)h3);
                *(short4*)(rlp + e*4) = make_short4((short)f2bf(res4.x - bf2f(h0)),
                                                    (short)f2bf(res4.y - bf2f(h1)),
                                                    (short)f2bf(res4.z - bf2f(h2)),
                                                    (short)f2bf(res4.w - bf2f(h3)));
            }
#pragma unroll
            for (int m = 1; m < 16; m <<= 1) rns += __shfl_xor(rns, m, 64);
            if (tx == 0) rnS[t] = rns;
        }
        // deterministic loss partial (f64)
#pragma unroll
        for (int m = 1; m < 64; m <<= 1) lacc += __shfl_xor(lacc, m, 64);
        __syncthreads();
        if ((tid & 63) == 0) lredD[tid >> 6] = lacc;
        __syncthreads();
        if (tid == 0)
            lpD[((size_t)g * Q + q) * 256 + blockIdx.x] =
                ((lredD[0] + lredD[1]) + (lredD[2] + lredD[3]));
        __syncthreads();
    }
}

// ---------------- K4: output projection out = qout @ Wout_g^T + bout ----------------
__global__ __launch_bounds__(256) void k_proj_out(const float* __restrict__ ws,
                                                  const float* __restrict__ Wout,
                                                  const float* __restrict__ bout,
                                                  float* __restrict__ out) {
    __shared__ float As[32][65];
    __shared__ float Bs[32][65];
    const int g  = blockIdx.z;
    const int t0 = blockIdx.x * 64;
    const int d0 = blockIdx.y * 64;
    const int tid = threadIdx.x;
    const int tx = tid & 15, ty = tid >> 4;
    float acc[4][4] = {};
    const float* Ab = ws + WS_H + ((size_t)g * T + t0) * CD;
    const float* Bb = Wout + (size_t)g * DG * CD + (size_t)d0 * CD;

    for (int k0 = 0; k0 < CD; k0 += 32) {
        __syncthreads();
#pragma unroll
        for (int j = 0; j < 8; j++) {
            int lin = j * 256 + tid;
            int k = lin & 31, r = lin >> 5;
            As[k][r] = Ab[(size_t)r * CD + k0 + k];
            Bs[k][r] = Bb[(size_t)r * CD + k0 + k];
        }
        __syncthreads();
#pragma unroll
        for (int k = 0; k < 32; k++) {
            float a[4], b[4];
#pragma unroll
            for (int i = 0; i < 4; i++) a[i] = As[k][ty + 16 * i];
#pragma unroll
            for (int j = 0; j < 4; j++) b[j] = Bs[k][tx + 16 * j];
#pragma unroll
            for (int i = 0; i < 4; i++)
#pragma unroll
                for (int j = 0; j < 4; j++) acc[i][j] = fmaf(a[i], b[j], acc[i][j]);
        }
    }
#pragma unroll
    for (int i = 0; i < 4; i++) {
        int t = t0 + ty + 16 * i;
#pragma unroll
        for (int j = 0; j < 4; j++) {
            int d = d0 + tx + 16 * j;
            out[(size_t)t * DIMV + (size_t)g * DG + d] = acc[i][j] + bout[g * DG + d];
        }
    }
}

// ---------------- K5: deterministic loss reduction (f64 -> f32) ----------------
__global__ void k_loss(const float* __restrict__ ws, float* __restrict__ out) {
    int gq = blockIdx.x;
    const double* lpD = (const double*)(ws + WS_LPARTD);
    double v = lpD[(size_t)gq * 256 + threadIdx.x];
#pragma unroll
    for (int m = 1; m < 64; m <<= 1) v += __shfl_xor(v, m, 64);
    __shared__ double red[4];
    if ((threadIdx.x & 63) == 0) red[threadIdx.x >> 6] = v;
    __syncthreads();
    if (threadIdx.x == 0)
        out[OUT_LOSS + gq] =
            (float)(((red[0] + red[1]) + (red[2] + red[3])) * (1.0 / 8388608.0));
}

extern "C" void kernel_launch(void* const* d_in, const int* in_sizes, int n_in,
                              void* d_out, int out_size, void* d_ws, size_t ws_size,
                              hipStream_t stream) {
    const float* x    = (const float*)d_in[0];
    const float* Win  = (const float*)d_in[1];
    const float* bin  = (const float*)d_in[2];
    const float* Wout = (const float*)d_in[3];
    const float* bout = (const float*)d_in[4];
    const float* cb   = (const float*)d_in[5];
    float* out = (float*)d_out;
    float* ws  = (float*)d_ws;

    // bf16 hi/lo scratch lives in the (not-yet-written) quantized region of d_out:
    // 2*G*T*CD + 2*G*Q*K*CD = 41.9M bf16 = 21.0M f32-equiv < 41.9M f32 region.
    short* scr  = (short*)d_out;
    short* resh = scr;
    short* resl = scr + (size_t)G * T * CD;
    short* cbh  = scr + (size_t)2 * G * T * CD;
    short* cbl  = cbh + (size_t)G * Q * KCODES * CD;

    hipLaunchKernelGGL(k_norms,    dim3(64),          dim3(256), 0, stream, cb, ws);
    hipLaunchKernelGGL(k_split,    dim3(4096),        dim3(256), 0, stream, cb, cbh, cbl);
    hipLaunchKernelGGL(k_proj_in,  dim3(T/64, 4, G),  dim3(256), 0, stream, x, Win, bin, ws, resh, resl);
    hipLaunchKernelGGL(k_rvq,      dim3(T/TM, G),     dim3(256), 0, stream, cb, ws, out, resh, resl, cbh, cbl);
    hipLaunchKernelGGL(k_proj_out, dim3(T/64, 10, G), dim3(256), 0, stream, ws, Wout, bout, out);
    hipLaunchKernelGGL(k_loss,     dim3(16),          dim3(256), 0, stream, ws, out);
}

// Round 6
// 3449.473 us; speedup vs baseline: 1.9098x; 1.2009x over previous
//
#include <hip/hip_runtime.h>
#include <hip/hip_bf16.h>

// Grouped Residual VQ: G=2, Q=8, K=1024, CD=256, DIM=1280 (DG=640), T=32768.
//
// Fast path: distance GEMM via bf16 3-term split MFMA (error ~1e-4 << EPS);
// tokens with (second-best - best) < EPS get an exact f64 rescan of all 1024
// codes. Score = ||c||^2 - 2 r.c (rn dropped: argmin/gap are rn-invariant).
// STE elementwise rounding replicated (quant = fl(r + fl(c-r)), etc).
//
// k_rvq pipeline: 32 phases/q (8 code-chunks x 4 dim-chunks), A+B double-
// buffered in LDS, staged by global_load_lds (16B) with pre-swizzled source
// addresses, raw s_barrier + counted vmcnt(16) so prefetch stays in flight.

#define G 2
#define Q 8
#define KCODES 1024
#define CD 256
#define DIMV 1280
#define DG 640
#define T 32768
#define TM 128

#define WS_H      ((size_t)0)
#define WS_RES    (WS_H + (size_t)G*T*CD)
#define WS_CNORM  (WS_RES + (size_t)G*T*CD)
#define WS_CN64   (WS_CNORM + (size_t)G*Q*KCODES)
#define WS_LPARTD (WS_CN64 + (size_t)2*G*Q*KCODES)

#define OUT_IDX   ((size_t)T*DIMV)
#define OUT_LOSS  (OUT_IDX + (size_t)G*T*Q)

#define EPS_REFINE 2e-3f

typedef __attribute__((ext_vector_type(8))) short s16x8;
typedef __attribute__((ext_vector_type(4))) float f32x4;

static __device__ __forceinline__ unsigned short f2bf(float v) {
    __hip_bfloat16 b = __float2bfloat16(v);
    return *(unsigned short*)&b;
}
static __device__ __forceinline__ float bf2f(unsigned short u) {
    __hip_bfloat16 b = *(__hip_bfloat16*)&u;
    return __bfloat162float(b);
}

static __device__ __forceinline__ void gl_lds16(const void* g, void* l) {
    __builtin_amdgcn_global_load_lds(
        (const __attribute__((address_space(1))) unsigned int*)g,
        (__attribute__((address_space(3))) unsigned int*)l, 16, 0, 0);
}

__device__ __forceinline__ float np_half_sumsq(const float4* __restrict__ p) {
    float4 a = p[0], b = p[1];
    float r0=a.x*a.x, r1=a.y*a.y, r2=a.z*a.z, r3=a.w*a.w;
    float r4=b.x*b.x, r5=b.y*b.y, r6=b.z*b.z, r7=b.w*b.w;
#pragma unroll
    for (int i = 1; i < 16; i++) {
        a = p[2*i]; b = p[2*i+1];
        r0 += a.x*a.x; r1 += a.y*a.y; r2 += a.z*a.z; r3 += a.w*a.w;
        r4 += b.x*b.x; r5 += b.y*b.y; r6 += b.z*b.z; r7 += b.w*b.w;
    }
    return ((r0+r1)+(r2+r3)) + ((r4+r5)+(r6+r7));
}

// ---------------- K1: codebook norms (f32 + exact f64) ----------------
__global__ void k_norms(const float* __restrict__ cb, float* __restrict__ ws) {
    int r = blockIdx.x * 256 + threadIdx.x;
    const float4* row = (const float4*)(cb + (size_t)r * CD);
    ws[WS_CNORM + r] = np_half_sumsq(row) + np_half_sumsq(row + 32);
    double s0=0, s1=0, s2=0, s3=0;
#pragma unroll 8
    for (int e = 0; e < 64; e++) {
        float4 v = row[e];
        s0 = fma((double)v.x,(double)v.x,s0); s1 = fma((double)v.y,(double)v.y,s1);
        s2 = fma((double)v.z,(double)v.z,s2); s3 = fma((double)v.w,(double)v.w,s3);
    }
    ((double*)(ws + WS_CN64))[r] = (s0+s1)+(s2+s3);
}

// ---------------- K1b: codebook bf16 hi/lo split ----------------
__global__ void k_split(const float* __restrict__ cb, short* __restrict__ cbh,
                        short* __restrict__ cbl) {
    size_t i = ((size_t)blockIdx.x * 256 + threadIdx.x) * 4;
    float4 v = *(const float4*)(cb + i);
    unsigned short h0=f2bf(v.x), h1=f2bf(v.y), h2=f2bf(v.z), h3=f2bf(v.w);
    *(short4*)(cbh + i) = make_short4((short)h0,(short)h1,(short)h2,(short)h3);
    *(short4*)(cbl + i) = make_short4((short)f2bf(v.x - bf2f(h0)), (short)f2bf(v.y - bf2f(h1)),
                                      (short)f2bf(v.z - bf2f(h2)), (short)f2bf(v.w - bf2f(h3)));
}

// ---------------- K2: input projection h = x_g @ Win_g^T + bin (+ bf16 split) ----------------
__global__ __launch_bounds__(256) void k_proj_in(const float* __restrict__ x,
                                                 const float* __restrict__ Win,
                                                 const float* __restrict__ bin,
                                                 float* __restrict__ ws,
                                                 short* __restrict__ resh,
                                                 short* __restrict__ resl) {
    __shared__ float As[32][65];
    __shared__ float Bs[32][65];
    const int g  = blockIdx.z;
    const int t0 = blockIdx.x * 64;
    const int c0 = blockIdx.y * 64;
    const int tid = threadIdx.x;
    const int tx = tid & 15, ty = tid >> 4;
    float acc[4][4] = {};
    const float* Ab = x + (size_t)t0 * DIMV + (size_t)g * DG;
    const float* Bb = Win + (size_t)g * CD * DG + (size_t)c0 * DG;

    for (int k0 = 0; k0 < DG; k0 += 32) {
        __syncthreads();
#pragma unroll
        for (int j = 0; j < 8; j++) {
            int lin = j * 256 + tid;
            int k = lin & 31, r = lin >> 5;
            As[k][r] = Ab[(size_t)r * DIMV + k0 + k];
            Bs[k][r] = Bb[(size_t)r * DG + k0 + k];
        }
        __syncthreads();
#pragma unroll
        for (int k = 0; k < 32; k++) {
            float a[4], b[4];
#pragma unroll
            for (int i = 0; i < 4; i++) a[i] = As[k][ty + 16 * i];
#pragma unroll
            for (int j = 0; j < 4; j++) b[j] = Bs[k][tx + 16 * j];
#pragma unroll
            for (int i = 0; i < 4; i++)
#pragma unroll
                for (int j = 0; j < 4; j++) acc[i][j] = fmaf(a[i], b[j], acc[i][j]);
        }
    }
#pragma unroll
    for (int i = 0; i < 4; i++) {
        int t = t0 + ty + 16 * i;
        size_t roff = ((size_t)g * T + t) * CD;
        float* hrow = ws + WS_H + roff;
#pragma unroll
        for (int j = 0; j < 4; j++) {
            int c = c0 + tx + 16 * j;
            float v = acc[i][j] + bin[g * CD + c];
            hrow[c] = v;
            unsigned short hb = f2bf(v);
            resh[roff + c] = (short)hb;
            resl[roff + c] = (short)f2bf(v - bf2f(hb));
        }
    }
}

// ---------------- K3: fused ResidualVQ (pipelined MFMA fast path) ----------------
__global__ __launch_bounds__(256) void k_rvq(const float* __restrict__ cb,
                                             float* __restrict__ ws,
                                             float* __restrict__ out,
                                             short* __restrict__ resh,
                                             short* __restrict__ resl,
                                             const short* __restrict__ cbh,
                                             const short* __restrict__ cbl) {
    __shared__ s16x8 AsV[2][2048];     // [buf][plane*1024 + row*8 + u_phys], 32 KB each
    __shared__ s16x8 BsV[2][2048];
    __shared__ float cnS[KCODES];
    __shared__ float mmv1[TM], mmv2[TM];
    __shared__ int   mmi[TM];
    __shared__ double lredD[4];

    const int g  = blockIdx.y;
    const int t0 = blockIdx.x * TM;
    const int tid = threadIdx.x;
    const int lane = tid & 63, l15 = lane & 15, l4 = lane >> 4;
    const int w = tid >> 6, wy = w >> 1, wx = w & 1;
    const int tx = tid & 15, ty = tid >> 4;
    const size_t gT = (size_t)g * T;
    float* hbuf = ws + WS_H;                       // qout accumulator
    float* rbuf = ws + WS_RES;
    const float* cng = ws + WS_CNORM + (size_t)g * Q * KCODES;
    double* lpD = (double*)(ws + WS_LPARTD);

    // per-thread staging geometry: load k covers LDS units [(w*8+k)*64, +64),
    // this lane owns unit n; source address pre-swizzled (u_phys = c8 ^ (row&7))
    size_t aoff[8], boff[8];
    int pl[8];
#pragma unroll
    for (int k = 0; k < 8; k++) {
        int n = (w * 8 + k) * 64 + lane;
        pl[k] = n >> 10;
        int m = n & 1023;
        int row = m >> 3, u = m & 7, c8 = u ^ (row & 7);
        aoff[k] = (gT + t0 + row) * CD + (size_t)(c8 * 8);
        boff[k] = (size_t)row * CD + (size_t)(c8 * 8);
    }

    for (int q = 0; q < Q; q++) {
        const float* cnq = cng + (size_t)q * KCODES;
        const double* cn64q = (const double*)(ws + WS_CN64) + ((size_t)g * Q + q) * KCODES;
        const float* cqb = cb + ((size_t)g * Q + q) * KCODES * CD;
        const short* cbhq = cbh + ((size_t)g * Q + q) * KCODES * CD;
        const short* cblq = cbl + ((size_t)g * Q + q) * KCODES * CD;
        const float* rsrc = (q == 0) ? hbuf : rbuf;

#pragma unroll
        for (int i = 0; i < 4; i++) cnS[i * 256 + tid] = cnq[i * 256 + tid];
        // prologue: stage phase 0 (cc=0, dc=0) into buf 0
#pragma unroll
        for (int k = 0; k < 8; k++)
            gl_lds16((pl[k] ? resl : resh) + aoff[k], &AsV[0][(w * 8 + k) * 64]);
#pragma unroll
        for (int k = 0; k < 8; k++)
            gl_lds16((pl[k] ? cblq : cbhq) + boff[k], &BsV[0][(w * 8 + k) * 64]);

        float tv1[16], tv2[16]; int tix[16];
#pragma unroll
        for (int e = 0; e < 16; e++) { tv1[e] = 3.4e38f; tv2[e] = 3.4e38f; tix[e] = 0x7fffffff; }

        f32x4 acc[4][4];
#pragma unroll
        for (int i = 0; i < 4; i++)
#pragma unroll
            for (int j = 0; j < 4; j++) acc[i][j] = (f32x4){0.f, 0.f, 0.f, 0.f};

        for (int p = 0; p < 32; p++) {
            const int buf = p & 1, cc = p >> 2, dc = p & 3;
            const int np = p + 1;
            __builtin_amdgcn_s_barrier();            // all waves done reading buf[np&1]
            if (np < 32) {
                const int nb = np & 1, ndc = np & 3;
                const size_t bq = (size_t)(np >> 2) * 128 * CD;
#pragma unroll
                for (int k = 0; k < 8; k++)
                    gl_lds16((pl[k] ? resl : resh) + aoff[k] + ndc * 64,
                             &AsV[nb][(w * 8 + k) * 64]);
#pragma unroll
                for (int k = 0; k < 8; k++)
                    gl_lds16((pl[k] ? cblq : cbhq) + bq + boff[k] + ndc * 64,
                             &BsV[nb][(w * 8 + k) * 64]);
                asm volatile("s_waitcnt vmcnt(16)" ::: "memory");   // phase p landed
            } else {
                asm volatile("s_waitcnt vmcnt(0)" ::: "memory");
            }
            __builtin_amdgcn_s_barrier();
            __builtin_amdgcn_sched_barrier(0);

#pragma unroll
            for (int ks = 0; ks < 2; ks++) {
                s16x8 ah[4], al[4];
#pragma unroll
                for (int ti = 0; ti < 4; ti++) {
                    int r = wy * 64 + ti * 16 + l15;
                    int u = (ks * 4 + l4) ^ (r & 7);
                    ah[ti] = AsV[buf][r * 8 + u];
                    al[ti] = AsV[buf][1024 + r * 8 + u];
                }
#pragma unroll
                for (int tj = 0; tj < 4; tj++) {
                    int r = wx * 64 + tj * 16 + l15;
                    int u = (ks * 4 + l4) ^ (r & 7);
                    s16x8 bh = BsV[buf][r * 8 + u];
                    s16x8 bl = BsV[buf][1024 + r * 8 + u];
#pragma unroll
                    for (int ti = 0; ti < 4; ti++) {
                        acc[ti][tj] = __builtin_amdgcn_mfma_f32_16x16x32_bf16(ah[ti], bh, acc[ti][tj], 0, 0, 0);
                        acc[ti][tj] = __builtin_amdgcn_mfma_f32_16x16x32_bf16(ah[ti], bl, acc[ti][tj], 0, 0, 0);
                        acc[ti][tj] = __builtin_amdgcn_mfma_f32_16x16x32_bf16(al[ti], bh, acc[ti][tj], 0, 0, 0);
                    }
                }
            }
            if (dc == 3) {      // score this code-chunk: vv = ||c||^2 - 2 r.c
#pragma unroll
                for (int tj = 0; tj < 4; tj++) {
                    int c = cc * 128 + wx * 64 + tj * 16 + l15;
                    float cnv = cnS[c];
#pragma unroll
                    for (int e = 0; e < 16; e++) {
                        float vv = fmaf(-2.f, acc[e >> 2][tj][e & 3], cnv);
                        if (vv < tv1[e]) { tv2[e] = tv1[e]; tv1[e] = vv; tix[e] = c; }
                        else tv2[e] = fminf(tv2[e], vv);
                    }
                }
#pragma unroll
                for (int i = 0; i < 4; i++)
#pragma unroll
                    for (int j = 0; j < 4; j++) acc[i][j] = (f32x4){0.f, 0.f, 0.f, 0.f};
            }
        }
        __syncthreads();

        // ---- cross-lane two-min butterfly (16 lanes share a token) ----
#pragma unroll
        for (int e = 0; e < 16; e++) {
            float v1 = tv1[e], v2 = tv2[e]; int i1 = tix[e];
#pragma unroll
            for (int m = 1; m < 16; m <<= 1) {
                float w1 = __shfl_xor(v1, m, 64);
                float w2 = __shfl_xor(v2, m, 64);
                int   j1 = __shfl_xor(i1, m, 64);
                if (w1 < v1)       { v2 = fminf(v1, w2); v1 = w1; i1 = j1; }
                else if (w1 == v1) { v2 = v1; if (j1 < i1) i1 = j1; }
                else               { v2 = fminf(v2, w1); }
            }
            tv1[e] = v1; tv2[e] = v2; tix[e] = i1;
        }
        // ---- cross-wave (wx halves) merge via LDS ----
        if (wx == 0 && l15 == 0) {
#pragma unroll
            for (int e = 0; e < 16; e++) {
                int tok = wy * 64 + (e >> 2) * 16 + l4 * 4 + (e & 3);
                mmv1[tok] = tv1[e]; mmv2[tok] = tv2[e]; mmi[tok] = tix[e];
            }
        }
        __syncthreads();
        if (wx == 1 && l15 == 0) {
#pragma unroll
            for (int e = 0; e < 16; e++) {
                int tok = wy * 64 + (e >> 2) * 16 + l4 * 4 + (e & 3);
                float a1 = mmv1[tok], a2 = mmv2[tok]; int ai = mmi[tok];
                float b1 = tv1[e], b2 = tv2[e]; int bi = tix[e];
                if (b1 < a1)       { a2 = fminf(a1, b2); a1 = b1; ai = bi; }
                else if (b1 == a1) { a2 = a1; if (bi < ai) ai = bi; }
                else               { a2 = fminf(a2, b1); }
                mmv1[tok] = a1; mmv2[tok] = a2; mmi[tok] = ai;
            }
        }
        __syncthreads();

        // ---- exact f64 refinement for near-tie tokens (rare) ----
        int besti[8];
#pragma unroll 1
        for (int i = 0; i < 8; i++) {
            int tok = ty + 16 * i;
            besti[i] = mmi[tok];
            if (!(mmv2[tok] - mmv1[tok] < EPS_REFINE)) continue;
            const float4* rp4 = (const float4*)(rsrc + (gT + t0 + tok) * CD);
            double bv = 1e300; int bi = 0x7fffffff;
            for (int c = tx; c < KCODES; c += 16) {
                const float4* cp4 = (const float4*)(cqb + (size_t)c * CD);
                double a0=0, a1=0, a2=0, a3=0;
#pragma unroll 4
                for (int e = 0; e < 64; e++) {
                    float4 cv = cp4[e], rv = rp4[e];
                    a0 = fma((double)rv.x,(double)cv.x,a0); a1 = fma((double)rv.y,(double)cv.y,a1);
                    a2 = fma((double)rv.z,(double)cv.z,a2); a3 = fma((double)rv.w,(double)cv.w,a3);
                }
                double dd = fma(-2.0, (a0+a1)+(a2+a3), cn64q[c]);
                if (dd < bv) { bv = dd; bi = c; }
            }
#pragma unroll
            for (int m = 1; m < 16; m <<= 1) {
                double ov = __shfl_xor(bv, m, 64);
                int    oi = __shfl_xor(bi, m, 64);
                if (ov < bv || (ov == bv && oi < bi)) { bv = ov; bi = oi; }
            }
            besti[i] = bi;
        }

        // ---- idx out ----
        if (tx == 0) {
#pragma unroll
            for (int i = 0; i < 8; i++)
                out[OUT_IDX + (gT + t0 + ty + 16 * i) * Q + q] = (float)besti[i];
        }

        // ---- STE epilogue: res/qout rounding-replicated; bf16 split fused ----
        double lacc = 0.0;
#pragma unroll
        for (int i = 0; i < 8; i++) {
            int t = ty + 16 * i;
            size_t off = (gT + t0 + t) * CD;
            const float4* cp = (const float4*)(cqb + (size_t)besti[i] * CD) + tx * 4;
            const float4* rp = (const float4*)(rsrc + off) + tx * 4;
            float4* wp = (float4*)(rbuf + off) + tx * 4;
            float4* qp = (float4*)(hbuf + off) + tx * 4;   // aliases rp when q==0 (per-thread RAW ok)
            short* rhp = resh + off + tx * 16;
            short* rlp = resl + off + tx * 16;
#pragma unroll
            for (int e = 0; e < 4; e++) {
                float4 c4 = cp[e], r4 = rp[e];
                float4 q4 = (q == 0) ? make_float4(0.f,0.f,0.f,0.f) : qp[e];
                float4 res4, qo4;
                float tt, qq, rr;
                tt = __fsub_rn(c4.x, r4.x); qq = __fadd_rn(r4.x, tt); rr = __fsub_rn(r4.x, qq);
                lacc += (double)rr * rr; res4.x = rr; qo4.x = (q==0) ? qq : __fadd_rn(q4.x, qq);
                tt = __fsub_rn(c4.y, r4.y); qq = __fadd_rn(r4.y, tt); rr = __fsub_rn(r4.y, qq);
                lacc += (double)rr * rr; res4.y = rr; qo4.y = (q==0) ? qq : __fadd_rn(q4.y, qq);
                tt = __fsub_rn(c4.z, r4.z); qq = __fadd_rn(r4.z, tt); rr = __fsub_rn(r4.z, qq);
                lacc += (double)rr * rr; res4.z = rr; qo4.z = (q==0) ? qq : __fadd_rn(q4.z, qq);
                tt = __fsub_rn(c4.w, r4.w); qq = __fadd_rn(r4.w, tt); rr = __fsub_rn(r4.w, qq);
                lacc += (double)rr * rr; res4.w = rr; qo4.w = (q==0) ? qq : __fadd_rn(q4.w, qq);
                wp[e] = res4;
                qp[e] = qo4;
                unsigned short h0=f2bf(res4.x), h1=f2bf(res4.y), h2=f2bf(res4.z), h3=f2bf(res4.w);
                *(short4*)(rhp + e*4) = make_short4((short)h0,(short)h1,(short)h2,(short)h3);
                *(short4*)(rlp + e*4) = make_short4((short)f2bf(res4.x - bf2f(h0)),
                                                    (short)f2bf(res4.y - bf2f(h1)),
                                                    (short)f2bf(res4.z - bf2f(h2)),
                                                    (short)f2bf(res4.w - bf2f(h3)));
            }
        }
        // deterministic loss partial (f64)
#pragma unroll
        for (int m = 1; m < 64; m <<= 1) lacc += __shfl_xor(lacc, m, 64);
        __syncthreads();
        if ((tid & 63) == 0) lredD[tid >> 6] = lacc;
        __syncthreads();
        if (tid == 0)
            lpD[((size_t)g * Q + q) * 256 + blockIdx.x] =
                ((lredD[0] + lredD[1]) + (lredD[2] + lredD[3]));
        __syncthreads();   // drains stores: next q's gl_lds reads resh/resl safely
    }
}

// ---------------- K4: output projection out = qout @ Wout_g^T + bout ----------------
__global__ __launch_bounds__(256) void k_proj_out(const float* __restrict__ ws,
                                                  const float* __restrict__ Wout,
                                                  const float* __restrict__ bout,
                                                  float* __restrict__ out) {
    __shared__ float As[32][65];
    __shared__ float Bs[32][65];
    const int g  = blockIdx.z;
    const int t0 = blockIdx.x * 64;
    const int d0 = blockIdx.y * 64;
    const int tid = threadIdx.x;
    const int tx = tid & 15, ty = tid >> 4;
    float acc[4][4] = {};
    const float* Ab = ws + WS_H + ((size_t)g * T + t0) * CD;
    const float* Bb = Wout + (size_t)g * DG * CD + (size_t)d0 * CD;

    for (int k0 = 0; k0 < CD; k0 += 32) {
        __syncthreads();
#pragma unroll
        for (int j = 0; j < 8; j++) {
            int lin = j * 256 + tid;
            int k = lin & 31, r = lin >> 5;
            As[k][r] = Ab[(size_t)r * CD + k0 + k];
            Bs[k][r] = Bb[(size_t)r * CD + k0 + k];
        }
        __syncthreads();
#pragma unroll
        for (int k = 0; k < 32; k++) {
            float a[4], b[4];
#pragma unroll
            for (int i = 0; i < 4; i++) a[i] = As[k][ty + 16 * i];
#pragma unroll
            for (int j = 0; j < 4; j++) b[j] = Bs[k][tx + 16 * j];
#pragma unroll
            for (int i = 0; i < 4; i++)
#pragma unroll
                for (int j = 0; j < 4; j++) acc[i][j] = fmaf(a[i], b[j], acc[i][j]);
        }
    }
#pragma unroll
    for (int i = 0; i < 4; i++) {
        int t = t0 + ty + 16 * i;
#pragma unroll
        for (int j = 0; j < 4; j++) {
            int d = d0 + tx + 16 * j;
            out[(size_t)t * DIMV + (size_t)g * DG + d] = acc[i][j] + bout[g * DG + d];
        }
    }
}

// ---------------- K5: deterministic loss reduction (f64 -> f32) ----------------
__global__ void k_loss(const float* __restrict__ ws, float* __restrict__ out) {
    int gq = blockIdx.x;
    const double* lpD = (const double*)(ws + WS_LPARTD);
    double v = lpD[(size_t)gq * 256 + threadIdx.x];
#pragma unroll
    for (int m = 1; m < 64; m <<= 1) v += __shfl_xor(v, m, 64);
    __shared__ double red[4];
    if ((threadIdx.x & 63) == 0) red[threadIdx.x >> 6] = v;
    __syncthreads();
    if (threadIdx.x == 0)
        out[OUT_LOSS + gq] =
            (float)(((red[0] + red[1]) + (red[2] + red[3])) * (1.0 / 8388608.0));
}

extern "C" void kernel_launch(void* const* d_in, const int* in_sizes, int n_in,
                              void* d_out, int out_size, void* d_ws, size_t ws_size,
                              hipStream_t stream) {
    const float* x    = (const float*)d_in[0];
    const float* Win  = (const float*)d_in[1];
    const float* bin  = (const float*)d_in[2];
    const float* Wout = (const float*)d_in[3];
    const float* bout = (const float*)d_in[4];
    const float* cb   = (const float*)d_in[5];
    float* out = (float*)d_out;
    float* ws  = (float*)d_ws;

    // bf16 hi/lo scratch in the not-yet-written quantized region of d_out:
    // 2*G*T*CD + 2*G*Q*K*CD bf16 = 21.0M f32-equiv < 41.9M f32 region.
    short* scr  = (short*)d_out;
    short* resh = scr;
    short* resl = scr + (size_t)G * T * CD;
    short* cbh  = scr + (size_t)2 * G * T * CD;
    short* cbl  = cbh + (size_t)G * Q * KCODES * CD;

    hipLaunchKernelGGL(k_norms,    dim3(64),          dim3(256), 0, stream, cb, ws);
    hipLaunchKernelGGL(k_split,    dim3(4096),        dim3(256), 0, stream, cb, cbh, cbl);
    hipLaunchKernelGGL(k_proj_in,  dim3(T/64, 4, G),  dim3(256), 0, stream, x, Win, bin, ws, resh, resl);
    hipLaunchKernelGGL(k_rvq,      dim3(T/TM, G),     dim3(256), 0, stream, cb, ws, out, resh, resl, cbh, cbl);
    hipLaunchKernelGGL(k_proj_out, dim3(T/64, 10, G), dim3(256), 0, stream, ws, Wout, bout, out);
    hipLaunchKernelGGL(k_loss,     dim3(16),          dim3(256), 0, stream, ws, out);
}

// Round 9
// 2838.035 us; speedup vs baseline: 2.3213x; 1.2154x over previous
//
#include <hip/hip_runtime.h>
#include <hip/hip_bf16.h>

// Grouped Residual VQ: G=2, Q=8, K=1024, CD=256, DIM=1280 (DG=640), T=32768.
//
// Fast path: distance GEMM via bf16 3-term split MFMA (error ~1e-4 << EPS);
// tokens with (second-best - best) < EPS get an exact f64 rescan of all 1024
// codes. Score = ||c||^2 - 2 r.c (rn dropped: argmin/gap are rn-invariant).
// STE elementwise rounding replicated (quant = fl(r + fl(c-r)), etc).
// quantized output = h - res_final (computed in k_proj_out), so the epilogue
// no longer maintains a qout accumulator.
//
// k_rvq: 64 phases/q (8 code-chunks x 8 dim-chunks of 32), A+B double-
// buffered in LDS (70 KB total -> 2 blocks/CU for TLP), staged by
// global_load_lds (16B) with pre-swizzled sources, raw s_barrier +
// counted vmcnt(8) so prefetch stays in flight.

#define G 2
#define Q 8
#define KCODES 1024
#define CD 256
#define DIMV 1280
#define DG 640
#define T 32768
#define TM 128

#define WS_H      ((size_t)0)
#define WS_RES    (WS_H + (size_t)G*T*CD)
#define WS_CNORM  (WS_RES + (size_t)G*T*CD)
#define WS_CN64   (WS_CNORM + (size_t)G*Q*KCODES)
#define WS_LPARTD (WS_CN64 + (size_t)2*G*Q*KCODES)

#define OUT_IDX   ((size_t)T*DIMV)
#define OUT_LOSS  (OUT_IDX + (size_t)G*T*Q)

#define EPS_REFINE 2e-3f

typedef __attribute__((ext_vector_type(8))) short s16x8;
typedef __attribute__((ext_vector_type(4))) float f32x4;

static __device__ __forceinline__ unsigned short f2bf(float v) {
    __hip_bfloat16 b = __float2bfloat16(v);
    return *(unsigned short*)&b;
}
static __device__ __forceinline__ float bf2f(unsigned short u) {
    __hip_bfloat16 b = *(__hip_bfloat16*)&u;
    return __bfloat162float(b);
}

static __device__ __forceinline__ void gl_lds16(const void* g, void* l) {
    __builtin_amdgcn_global_load_lds(
        (const __attribute__((address_space(1))) unsigned int*)g,
        (__attribute__((address_space(3))) unsigned int*)l, 16, 0, 0);
}

__device__ __forceinline__ float np_half_sumsq(const float4* __restrict__ p) {
    float4 a = p[0], b = p[1];
    float r0=a.x*a.x, r1=a.y*a.y, r2=a.z*a.z, r3=a.w*a.w;
    float r4=b.x*b.x, r5=b.y*b.y, r6=b.z*b.z, r7=b.w*b.w;
#pragma unroll
    for (int i = 1; i < 16; i++) {
        a = p[2*i]; b = p[2*i+1];
        r0 += a.x*a.x; r1 += a.y*a.y; r2 += a.z*a.z; r3 += a.w*a.w;
        r4 += b.x*b.x; r5 += b.y*b.y; r6 += b.z*b.z; r7 += b.w*b.w;
    }
    return ((r0+r1)+(r2+r3)) + ((r4+r5)+(r6+r7));
}

// ---------------- K1: codebook norms (f32 + exact f64) ----------------
__global__ void k_norms(const float* __restrict__ cb, float* __restrict__ ws) {
    int r = blockIdx.x * 256 + threadIdx.x;
    const float4* row = (const float4*)(cb + (size_t)r * CD);
    ws[WS_CNORM + r] = np_half_sumsq(row) + np_half_sumsq(row + 32);
    double s0=0, s1=0, s2=0, s3=0;
#pragma unroll 8
    for (int e = 0; e < 64; e++) {
        float4 v = row[e];
        s0 = fma((double)v.x,(double)v.x,s0); s1 = fma((double)v.y,(double)v.y,s1);
        s2 = fma((double)v.z,(double)v.z,s2); s3 = fma((double)v.w,(double)v.w,s3);
    }
    ((double*)(ws + WS_CN64))[r] = (s0+s1)+(s2+s3);
}

// ---------------- K1b: codebook bf16 hi/lo split ----------------
__global__ void k_split(const float* __restrict__ cb, short* __restrict__ cbh,
                        short* __restrict__ cbl) {
    size_t i = ((size_t)blockIdx.x * 256 + threadIdx.x) * 4;
    float4 v = *(const float4*)(cb + i);
    unsigned short h0=f2bf(v.x), h1=f2bf(v.y), h2=f2bf(v.z), h3=f2bf(v.w);
    *(short4*)(cbh + i) = make_short4((short)h0,(short)h1,(short)h2,(short)h3);
    *(short4*)(cbl + i) = make_short4((short)f2bf(v.x - bf2f(h0)), (short)f2bf(v.y - bf2f(h1)),
                                      (short)f2bf(v.z - bf2f(h2)), (short)f2bf(v.w - bf2f(h3)));
}

// ---------------- K2: input projection h = x_g @ Win_g^T + bin (+ bf16 split) ----------------
__global__ __launch_bounds__(256) void k_proj_in(const float* __restrict__ x,
                                                 const float* __restrict__ Win,
                                                 const float* __restrict__ bin,
                                                 float* __restrict__ ws,
                                                 short* __restrict__ resh,
                                                 short* __restrict__ resl) {
    __shared__ float As[32][65];
    __shared__ float Bs[32][65];
    const int g  = blockIdx.z;
    const int t0 = blockIdx.x * 64;
    const int c0 = blockIdx.y * 64;
    const int tid = threadIdx.x;
    const int tx = tid & 15, ty = tid >> 4;
    float acc[4][4] = {};
    const float* Ab = x + (size_t)t0 * DIMV + (size_t)g * DG;
    const float* Bb = Win + (size_t)g * CD * DG + (size_t)c0 * DG;

    for (int k0 = 0; k0 < DG; k0 += 32) {
        __syncthreads();
#pragma unroll
        for (int j = 0; j < 8; j++) {
            int lin = j * 256 + tid;
            int k = lin & 31, r = lin >> 5;
            As[k][r] = Ab[(size_t)r * DIMV + k0 + k];
            Bs[k][r] = Bb[(size_t)r * DG + k0 + k];
        }
        __syncthreads();
#pragma unroll
        for (int k = 0; k < 32; k++) {
            float a[4], b[4];
#pragma unroll
            for (int i = 0; i < 4; i++) a[i] = As[k][ty + 16 * i];
#pragma unroll
            for (int j = 0; j < 4; j++) b[j] = Bs[k][tx + 16 * j];
#pragma unroll
            for (int i = 0; i < 4; i++)
#pragma unroll
                for (int j = 0; j < 4; j++) acc[i][j] = fmaf(a[i], b[j], acc[i][j]);
        }
    }
#pragma unroll
    for (int i = 0; i < 4; i++) {
        int t = t0 + ty + 16 * i;
        size_t roff = ((size_t)g * T + t) * CD;
        float* hrow = ws + WS_H + roff;
#pragma unroll
        for (int j = 0; j < 4; j++) {
            int c = c0 + tx + 16 * j;
            float v = acc[i][j] + bin[g * CD + c];
            hrow[c] = v;
            unsigned short hb = f2bf(v);
            resh[roff + c] = (short)hb;
            resl[roff + c] = (short)f2bf(v - bf2f(hb));
        }
    }
}

// ---------------- K3: fused ResidualVQ (pipelined MFMA, 2 blocks/CU) ----------------
__global__ __launch_bounds__(256, 2) void k_rvq(const float* __restrict__ cb,
                                                float* __restrict__ ws,
                                                float* __restrict__ out,
                                                short* __restrict__ resh,
                                                short* __restrict__ resl,
                                                const short* __restrict__ cbh,
                                                const short* __restrict__ cbl) {
    __shared__ s16x8 AsV[2][1024];     // [buf][pl*512 + row*4 + phys], 16 KB each
    __shared__ s16x8 BsV[2][1024];
    __shared__ float cnS[KCODES];
    __shared__ float mmv1[TM], mmv2[TM];
    __shared__ int   mmi[TM];
    __shared__ double lredD[4];

    const int g  = blockIdx.y;
    const int t0 = blockIdx.x * TM;
    const int tid = threadIdx.x;
    const int lane = tid & 63, l15 = lane & 15, l4 = lane >> 4;
    const int w = tid >> 6, wy = w >> 1, wx = w & 1;
    const int tx = tid & 15, ty = tid >> 4;
    const size_t gT = (size_t)g * T;
    float* hbuf = ws + WS_H;                       // h (read-only; NOT overwritten)
    float* rbuf = ws + WS_RES;
    const float* cng = ws + WS_CNORM + (size_t)g * Q * KCODES;
    double* lpD = (double*)(ws + WS_LPARTD);

    // staging geometry: load k fills LDS units [(w*4+k)*64, +64); this lane
    // owns unit n. Dest is linear; source is pre-swizzled (phys = c8 ^ swz).
    size_t aoff[4], boff[4];
    int pl[4];
#pragma unroll
    for (int k = 0; k < 4; k++) {
        int n = (w * 4 + k) * 64 + lane;
        pl[k] = n >> 9;
        int m = n & 511;
        int row = m >> 2, phys = m & 3, c8 = phys ^ ((row >> 1) & 3);
        aoff[k] = (gT + t0 + row) * CD + (size_t)(c8 * 8);
        boff[k] = (size_t)row * CD + (size_t)(c8 * 8);
    }

    for (int q = 0; q < Q; q++) {
        const float* cnq = cng + (size_t)q * KCODES;
        const double* cn64q = (const double*)(ws + WS_CN64) + ((size_t)g * Q + q) * KCODES;
        const float* cqb = cb + ((size_t)g * Q + q) * KCODES * CD;
        const short* cbhq = cbh + ((size_t)g * Q + q) * KCODES * CD;
        const short* cblq = cbl + ((size_t)g * Q + q) * KCODES * CD;
        const float* rsrc = (q == 0) ? hbuf : rbuf;

#pragma unroll
        for (int i = 0; i < 4; i++) cnS[i * 256 + tid] = cnq[i * 256 + tid];
        asm volatile("s_waitcnt vmcnt(0)" ::: "memory");   // clean slate for counted waits
        // prologue: stage phase 0 (cc=0, dc=0) into buf 0
#pragma unroll
        for (int k = 0; k < 4; k++)
            gl_lds16((pl[k] ? resl : resh) + aoff[k], &AsV[0][(w * 4 + k) * 64]);
#pragma unroll
        for (int k = 0; k < 4; k++)
            gl_lds16((pl[k] ? cblq : cbhq) + boff[k], &BsV[0][(w * 4 + k) * 64]);

        float tv1[16], tv2[16]; int tix[16];
#pragma unroll
        for (int e = 0; e < 16; e++) { tv1[e] = 3.4e38f; tv2[e] = 3.4e38f; tix[e] = 0x7fffffff; }

        f32x4 acc[4][4];
#pragma unroll
        for (int i = 0; i < 4; i++)
#pragma unroll
            for (int j = 0; j < 4; j++) acc[i][j] = (f32x4){0.f, 0.f, 0.f, 0.f};

        for (int p = 0; p < 64; p++) {
            const int buf = p & 1, cc = p >> 3, dc = p & 7;
            const int np = p + 1;
            __builtin_amdgcn_s_barrier();            // all waves done reading buf[np&1]
            if (np < 64) {
                const int nb = np & 1, ndc = np & 7;
                const size_t bq = (size_t)(np >> 3) * 128 * CD;
#pragma unroll
                for (int k = 0; k < 4; k++)
                    gl_lds16((pl[k] ? resl : resh) + aoff[k] + ndc * 32,
                             &AsV[nb][(w * 4 + k) * 64]);
#pragma unroll
                for (int k = 0; k < 4; k++)
                    gl_lds16((pl[k] ? cblq : cbhq) + bq + boff[k] + ndc * 32,
                             &BsV[nb][(w * 4 + k) * 64]);
                asm volatile("s_waitcnt vmcnt(8)" ::: "memory");    // phase p landed
            } else {
                asm volatile("s_waitcnt vmcnt(0)" ::: "memory");
            }
            __builtin_amdgcn_s_barrier();
            __builtin_amdgcn_sched_barrier(0);

            s16x8 ah[4], al[4];
#pragma unroll
            for (int ti = 0; ti < 4; ti++) {
                int r = wy * 64 + ti * 16 + l15;
                int u = l4 ^ ((r >> 1) & 3);
                ah[ti] = AsV[buf][r * 4 + u];
                al[ti] = AsV[buf][512 + r * 4 + u];
            }
#pragma unroll
            for (int tj = 0; tj < 4; tj++) {
                int r = wx * 64 + tj * 16 + l15;
                int u = l4 ^ ((r >> 1) & 3);
                s16x8 bh = BsV[buf][r * 4 + u];
                s16x8 bl = BsV[buf][512 + r * 4 + u];
#pragma unroll
                for (int ti = 0; ti < 4; ti++) {
                    acc[ti][tj] = __builtin_amdgcn_mfma_f32_16x16x32_bf16(ah[ti], bh, acc[ti][tj], 0, 0, 0);
                    acc[ti][tj] = __builtin_amdgcn_mfma_f32_16x16x32_bf16(ah[ti], bl, acc[ti][tj], 0, 0, 0);
                    acc[ti][tj] = __builtin_amdgcn_mfma_f32_16x16x32_bf16(al[ti], bh, acc[ti][tj], 0, 0, 0);
                }
            }
            if (dc == 7) {      // score this code-chunk: vv = ||c||^2 - 2 r.c
#pragma unroll
                for (int tj = 0; tj < 4; tj++) {
                    int c = cc * 128 + wx * 64 + tj * 16 + l15;
                    float cnv = cnS[c];
#pragma unroll
                    for (int e = 0; e < 16; e++) {
                        float vv = fmaf(-2.f, acc[e >> 2][tj][e & 3], cnv);
                        if (vv < tv1[e]) { tv2[e] = tv1[e]; tv1[e] = vv; tix[e] = c; }
                        else tv2[e] = fminf(tv2[e], vv);
                    }
                }
#pragma unroll
                for (int i = 0; i < 4; i++)
#pragma unroll
                    for (int j = 0; j < 4; j++) acc[i][j] = (f32x4){0.f, 0.f, 0.f, 0.f};
            }
        }
        __syncthreads();

        // ---- cross-lane two-min butterfly (16 lanes share a token) ----
#pragma unroll
        for (int e = 0; e < 16; e++) {
            float v1 = tv1[e], v2 = tv2[e]; int i1 = tix[e];
#pragma unroll
            for (int m = 1; m < 16; m <<= 1) {
                float w1 = __shfl_xor(v1, m, 64);
                float w2 = __shfl_xor(v2, m, 64);
                int   j1 = __shfl_xor(i1, m, 64);
                if (w1 < v1)       { v2 = fminf(v1, w2); v1 = w1; i1 = j1; }
                else if (w1 == v1) { v2 = v1; if (j1 < i1) i1 = j1; }
                else               { v2 = fminf(v2, w1); }
            }
            tv1[e] = v1; tv2[e] = v2; tix[e] = i1;
        }
        // ---- cross-wave (wx halves) merge via LDS ----
        if (wx == 0 && l15 == 0) {
#pragma unroll
            for (int e = 0; e < 16; e++) {
                int tok = wy * 64 + (e >> 2) * 16 + l4 * 4 + (e & 3);
                mmv1[tok] = tv1[e]; mmv2[tok] = tv2[e]; mmi[tok] = tix[e];
            }
        }
        __syncthreads();
        if (wx == 1 && l15 == 0) {
#pragma unroll
            for (int e = 0; e < 16; e++) {
                int tok = wy * 64 + (e >> 2) * 16 + l4 * 4 + (e & 3);
                float a1 = mmv1[tok], a2 = mmv2[tok]; int ai = mmi[tok];
                float b1 = tv1[e], b2 = tv2[e]; int bi = tix[e];
                if (b1 < a1)       { a2 = fminf(a1, b2); a1 = b1; ai = bi; }
                else if (b1 == a1) { a2 = a1; if (bi < ai) ai = bi; }
                else               { a2 = fminf(a2, b1); }
                mmv1[tok] = a1; mmv2[tok] = a2; mmi[tok] = ai;
            }
        }
        __syncthreads();

        // ---- exact f64 refinement for near-tie tokens (rare) ----
        int besti[8];
#pragma unroll 1
        for (int i = 0; i < 8; i++) {
            int tok = ty + 16 * i;
            besti[i] = mmi[tok];
            if (!(mmv2[tok] - mmv1[tok] < EPS_REFINE)) continue;
            const float4* rp4 = (const float4*)(rsrc + (gT + t0 + tok) * CD);
            double bv = 1e300; int bi = 0x7fffffff;
            for (int c = tx; c < KCODES; c += 16) {
                const float4* cp4 = (const float4*)(cqb + (size_t)c * CD);
                double a0=0, a1=0, a2=0, a3=0;
#pragma unroll 4
                for (int e = 0; e < 64; e++) {
                    float4 cv = cp4[e], rv = rp4[e];
                    a0 = fma((double)rv.x,(double)cv.x,a0); a1 = fma((double)rv.y,(double)cv.y,a1);
                    a2 = fma((double)rv.z,(double)cv.z,a2); a3 = fma((double)rv.w,(double)cv.w,a3);
                }
                double dd = fma(-2.0, (a0+a1)+(a2+a3), cn64q[c]);
                if (dd < bv) { bv = dd; bi = c; }
            }
#pragma unroll
            for (int m = 1; m < 16; m <<= 1) {
                double ov = __shfl_xor(bv, m, 64);
                int    oi = __shfl_xor(bi, m, 64);
                if (ov < bv || (ov == bv && oi < bi)) { bv = ov; bi = oi; }
            }
            besti[i] = bi;
        }

        // ---- idx out ----
        if (tx == 0) {
#pragma unroll
            for (int i = 0; i < 8; i++)
                out[OUT_IDX + (gT + t0 + ty + 16 * i) * Q + q] = (float)besti[i];
        }

        // ---- STE epilogue: res rounding-replicated; bf16 split fused; no qout ----
        double lacc = 0.0;
#pragma unroll
        for (int i = 0; i < 8; i++) {
            int t = ty + 16 * i;
            size_t off = (gT + t0 + t) * CD;
            const float4* cp = (const float4*)(cqb + (size_t)besti[i] * CD) + tx * 4;
            const float4* rp = (const float4*)(rsrc + off) + tx * 4;
            float4* wp = (float4*)(rbuf + off) + tx * 4;
            short* rhp = resh + off + tx * 16;
            short* rlp = resl + off + tx * 16;
#pragma unroll
            for (int e = 0; e < 4; e++) {
                float4 c4 = cp[e], r4 = rp[e];
                float4 res4;
                float tt, qq, rr;
                tt = __fsub_rn(c4.x, r4.x); qq = __fadd_rn(r4.x, tt); rr = __fsub_rn(r4.x, qq);
                lacc += (double)rr * rr; res4.x = rr;
                tt = __fsub_rn(c4.y, r4.y); qq = __fadd_rn(r4.y, tt); rr = __fsub_rn(r4.y, qq);
                lacc += (double)rr * rr; res4.y = rr;
                tt = __fsub_rn(c4.z, r4.z); qq = __fadd_rn(r4.z, tt); rr = __fsub_rn(r4.z, qq);
                lacc += (double)rr * rr; res4.z = rr;
                tt = __fsub_rn(c4.w, r4.w); qq = __fadd_rn(r4.w, tt); rr = __fsub_rn(r4.w, qq);
                lacc += (double)rr * rr; res4.w = rr;
                wp[e] = res4;
                unsigned short h0=f2bf(res4.x), h1=f2bf(res4.y), h2=f2bf(res4.z), h3=f2bf(res4.w);
                *(short4*)(rhp + e*4) = make_short4((short)h0,(short)h1,(short)h2,(short)h3);
                *(short4*)(rlp + e*4) = make_short4((short)f2bf(res4.x - bf2f(h0)),
                                                    (short)f2bf(res4.y - bf2f(h1)),
                                                    (short)f2bf(res4.z - bf2f(h2)),
                                                    (short)f2bf(res4.w - bf2f(h3)));
            }
        }
        // deterministic loss partial (f64)
#pragma unroll
        for (int m = 1; m < 64; m <<= 1) lacc += __shfl_xor(lacc, m, 64);
        __syncthreads();
        if ((tid & 63) == 0) lredD[tid >> 6] = lacc;
        __syncthreads();
        if (tid == 0)
            lpD[((size_t)g * Q + q) * 256 + blockIdx.x] =
                ((lredD[0] + lredD[1]) + (lredD[2] + lredD[3]));
        __syncthreads();   // drains stores: next q's gl_lds reads resh/resl safely
    }
}

// ---------------- K4: output projection out = (h - res) @ Wout_g^T + bout ----------------
__global__ __launch_bounds__(256) void k_proj_out(const float* __restrict__ ws,
                                                  const float* __restrict__ Wout,
                                                  const float* __restrict__ bout,
                                                  float* __restrict__ out) {
    __shared__ float As[32][65];
    __shared__ float Bs[32][65];
    const int g  = blockIdx.z;
    const int t0 = blockIdx.x * 64;
    const int d0 = blockIdx.y * 64;
    const int tid = threadIdx.x;
    const int tx = tid & 15, ty = tid >> 4;
    float acc[4][4] = {};
    const float* Ah = ws + WS_H + ((size_t)g * T + t0) * CD;
    const float* Ar = ws + WS_RES + ((size_t)g * T + t0) * CD;
    const float* Bb = Wout + (size_t)g * DG * CD + (size_t)d0 * CD;

    for (int k0 = 0; k0 < CD; k0 += 32) {
        __syncthreads();
#pragma unroll
        for (int j = 0; j < 8; j++) {
            int lin = j * 256 + tid;
            int k = lin & 31, r = lin >> 5;
            size_t o = (size_t)r * CD + k0 + k;
            As[k][r] = Ah[o] - Ar[o];            // qout = h - res_final
            Bs[k][r] = Bb[o];
        }
        __syncthreads();
#pragma unroll
        for (int k = 0; k < 32; k++) {
            float a[4], b[4];
#pragma unroll
            for (int i = 0; i < 4; i++) a[i] = As[k][ty + 16 * i];
#pragma unroll
            for (int j = 0; j < 4; j++) b[j] = Bs[k][tx + 16 * j];
#pragma unroll
            for (int i = 0; i < 4; i++)
#pragma unroll
                for (int j = 0; j < 4; j++) acc[i][j] = fmaf(a[i], b[j], acc[i][j]);
        }
    }
#pragma unroll
    for (int i = 0; i < 4; i++) {
        int t = t0 + ty + 16 * i;
#pragma unroll
        for (int j = 0; j < 4; j++) {
            int d = d0 + tx + 16 * j;
            out[(size_t)t * DIMV + (size_t)g * DG + d] = acc[i][j] + bout[g * DG + d];
        }
    }
}

// ---------------- K5: deterministic loss reduction (f64 -> f32) ----------------
__global__ void k_loss(const float* __restrict__ ws, float* __restrict__ out) {
    int gq = blockIdx.x;
    const double* lpD = (const double*)(ws + WS_LPARTD);
    double v = lpD[(size_t)gq * 256 + threadIdx.x];
#pragma unroll
    for (int m = 1; m < 64; m <<= 1) v += __shfl_xor(v, m, 64);
    __shared__ double red[4];
    if ((threadIdx.x & 63) == 0) red[threadIdx.x >> 6] = v;
    __syncthreads();
    if (threadIdx.x == 0)
        out[OUT_LOSS + gq] =
            (float)(((red[0] + red[1]) + (red[2] + red[3])) * (1.0 / 8388608.0));
}

extern "C" void kernel_launch(void* const* d_in, const int* in_sizes, int n_in,
                              void* d_out, int out_size, void* d_ws, size_t ws_size,
                              hipStream_t stream) {
    const float* x    = (const float*)d_in[0];
    const float* Win  = (const float*)d_in[1];
    const float* bin  = (const float*)d_in[2];
    const float* Wout = (const float*)d_in[3];
    const float* bout = (const float*)d_in[4];
    const float* cb   = (const float*)d_in[5];
    float* out = (float*)d_out;
    float* ws  = (float*)d_ws;

    // bf16 hi/lo scratch in the not-yet-written quantized region of d_out:
    // 2*G*T*CD + 2*G*Q*K*CD bf16 = 25.2M f32-equiv < 41.9M f32 region.
    short* scr  = (short*)d_out;
    short* resh = scr;
    short* resl = scr + (size_t)G * T * CD;
    short* cbh  = scr + (size_t)2 * G * T * CD;
    short* cbl  = cbh + (size_t)G * Q * KCODES * CD;

    hipLaunchKernelGGL(k_norms,    dim3(64),          dim3(256), 0, stream, cb, ws);
    hipLaunchKernelGGL(k_split,    dim3(4096),        dim3(256), 0, stream, cb, cbh, cbl);
    hipLaunchKernelGGL(k_proj_in,  dim3(T/64, 4, G),  dim3(256), 0, stream, x, Win, bin, ws, resh, resl);
    hipLaunchKernelGGL(k_rvq,      dim3(T/TM, G),     dim3(256), 0, stream, cb, ws, out, resh, resl, cbh, cbl);
    hipLaunchKernelGGL(k_proj_out, dim3(T/64, 10, G), dim3(256), 0, stream, ws, Wout, bout, out);
    hipLaunchKernelGGL(k_loss,     dim3(16),          dim3(256), 0, stream, ws, out);
}